// Round 4
// baseline (491.226 us; speedup 1.0000x reference)
//
#include <hip/hip_runtime.h>

typedef unsigned short ushort;
typedef unsigned int uint;
typedef __bf16 bf16x8 __attribute__((ext_vector_type(8)));
typedef unsigned short u16x8 __attribute__((ext_vector_type(8)));
typedef float f32x4 __attribute__((ext_vector_type(4)));

__device__ __forceinline__ ushort f2bf(float f) {
  uint u = __builtin_bit_cast(uint, f);
  u += 0x7fffu + ((u >> 16) & 1u);
  return (ushort)(u >> 16);
}

__device__ __forceinline__ f32x4 mfma_bf16(u16x8 a, u16x8 b, f32x4 c) {
  return __builtin_amdgcn_mfma_f32_16x16x32_bf16(
      __builtin_bit_cast(bf16x8, a), __builtin_bit_cast(bf16x8, b), c, 0, 0, 0);
}

// window-ordered row -> original token row (B=32, H=W=56, ws=7)
__device__ __forceinline__ uint win2orig(uint wr) {
  uint b = wr / 3136u, rem = wr % 3136u;
  uint g = rem / 49u, s = rem % 49u;
  return b * 3136u + ((g >> 3) * 7u + s / 7u) * 56u + (g & 7u) * 7u + s % 7u;
}

// x fp32 (orig order) -> xb bf16 (window order), 8 elems/thread
__global__ __launch_bounds__(256) void cvt_x_win(const float* __restrict__ X,
                                                 ushort* __restrict__ Xb, int total8) {
  int stride = gridDim.x * 256;
  for (int i = blockIdx.x * 256 + threadIdx.x; i < total8; i += stride) {
    uint wr = (uint)i >> 6, c8 = (uint)i & 63u;
    const float* xp = X + (size_t)win2orig(wr) * 512 + c8 * 8;
    f32x4 a = *(const f32x4*)xp;
    f32x4 b = *(const f32x4*)(xp + 4);
    u16x8 o;
#pragma unroll
    for (int j = 0; j < 4; ++j) { o[j] = f2bf(a[j]); o[j + 4] = f2bf(b[j]); }
    ((u16x8*)Xb)[i] = o;
  }
}

// W[K][N] fp32 -> WT[N][K] bf16, LDS-tiled 32x32
__global__ __launch_bounds__(256) void transpose_cvt(const float* __restrict__ W,
                                                     ushort* __restrict__ WT,
                                                     int K, int N) {
  __shared__ float t[32][33];
  const int tn0 = blockIdx.x * 32, tk0 = blockIdx.y * 32;
  const int tx = threadIdx.x & 31, ty = threadIdx.x >> 5;
#pragma unroll
  for (int i = 0; i < 4; ++i) {
    int k = tk0 + ty + i * 8;
    t[ty + i * 8][tx] = W[(size_t)k * N + tn0 + tx];
  }
  __syncthreads();
#pragma unroll
  for (int i = 0; i < 4; ++i) {
    int n = tn0 + ty + i * 8;
    WT[(size_t)n * K + tk0 + tx] = f2bf(t[tx][ty + i * 8]);
  }
}

// ---------------- 256x256 8-phase max-lead GEMM, K=512 ----------------
// One STAGE per phase, placed right after its region's reader phase ->
// every region has 6-7 phase stage->consume lead; uniform WAITV(10)
// keeps 5 stages (~4.5 phases) in flight, never drains to 0 mid-loop.
// OUT=0: bf16 store (ldc); OUT=1: f32+bias, rows descattered win->orig.

#define GLL(g, l)                                                              \
  __builtin_amdgcn_global_load_lds(                                            \
      (const __attribute__((address_space(1))) uint*)(g),                      \
      (__attribute__((address_space(3))) uint*)(l), 16, 0, 0)
#define BAR() __builtin_amdgcn_s_barrier()
#define SCB() __builtin_amdgcn_sched_barrier(0)
#define WAITV(n) asm volatile("s_waitcnt vmcnt(" #n ")" ::: "memory")

template <int OUT>
__global__ __launch_bounds__(512, 2) void gemm8p(const ushort* __restrict__ A,
                                                 const ushort* __restrict__ BT,
                                                 void* __restrict__ Cout,
                                                 const float* __restrict__ bias,
                                                 const int ldc, const int NT,
                                                 const int CPX) {
  __shared__ __align__(16) ushort as_[2][16384];
  __shared__ __align__(16) ushort bs_[2][16384];
  const int bid = blockIdx.x;
  const int wg = (bid & 7) * CPX + (bid >> 3);  // XCD swizzle (grid % 8 == 0)
  const int mt = wg / NT, nt = wg - mt * NT;    // ntile-inner: A-panel L2 reuse
  const int m0 = mt << 8, n0 = nt << 8;
  const int tid = threadIdx.x, lane = tid & 63, wid = tid >> 6;
  const int wm = wid >> 2, wn = wid & 3;
  const int c16 = lane & 15, q4 = lane >> 4;
  const int sw = c16 & 7;
  const int lrow = lane >> 3, lcg = (lane & 7) ^ lrow;  // stage src swizzle
  const ushort* Ag = A + (size_t)(m0 + wid * 16 + lrow) * 512 + lcg * 8;
  const ushort* Bg = BT + (size_t)(n0 + wid * 16 + lrow) * 512 + lcg * 8;
  const int aro = (wm * 64 + c16) * 64;
  const int bro = (wn * 32 + c16) * 64;
  const int ag0 = (q4 ^ sw) * 8;
  const int ag1 = ((4 + q4) ^ sw) * 8;

  f32x4 acc[8][4];
#pragma unroll
  for (int m = 0; m < 8; ++m)
#pragma unroll
    for (int n = 0; n < 4; ++n) acc[m][n] = f32x4{0.f, 0.f, 0.f, 0.f};
  u16x8 af[4][2], bf0[2][2], bf1[2][2];

#define STAGE_A(half, ktg)                                                     \
  do {                                                                         \
    const ushort* g_ = Ag + (size_t)(half) * (128 * 512) + (ktg) * 64;         \
    ushort* l_ = &as_[(ktg) & 1][(half) * 8192 + wid * 1024 + lane * 8];       \
    GLL(g_, l_);                                                               \
    GLL(g_ + 8 * 512, l_ + 512);                                               \
  } while (0)
#define STAGE_B(half, ktg)                                                     \
  do {                                                                         \
    const ushort* g_ = Bg + (size_t)(half) * (128 * 512) + (ktg) * 64;         \
    ushort* l_ = &bs_[(ktg) & 1][(half) * 8192 + wid * 1024 + lane * 8];       \
    GLL(g_, l_);                                                               \
    GLL(g_ + 8 * 512, l_ + 512);                                               \
  } while (0)
#define LDA(kt, mh)                                                            \
  do {                                                                         \
    const ushort* p_ = &as_[kt][(mh)*8192 + aro];                              \
    _Pragma("unroll") for (int f_ = 0; f_ < 4; ++f_) {                         \
      af[f_][0] = *(const u16x8*)(p_ + f_ * 1024 + ag0);                       \
      af[f_][1] = *(const u16x8*)(p_ + f_ * 1024 + ag1);                       \
    }                                                                          \
  } while (0)
#define LDB(kt, nh, BF)                                                        \
  do {                                                                         \
    const ushort* p_ = &bs_[kt][(nh)*8192 + bro];                              \
    _Pragma("unroll") for (int g_ = 0; g_ < 2; ++g_) {                         \
      BF[g_][0] = *(const u16x8*)(p_ + g_ * 1024 + ag0);                       \
      BF[g_][1] = *(const u16x8*)(p_ + g_ * 1024 + ag1);                       \
    }                                                                          \
  } while (0)
#define MM(mh, nh, BF)                                                         \
  do {                                                                         \
    __builtin_amdgcn_s_setprio(1);                                             \
    _Pragma("unroll") for (int f_ = 0; f_ < 4; ++f_)                           \
        _Pragma("unroll") for (int g_ = 0; g_ < 2; ++g_) {                     \
      f32x4& a_ = acc[(mh)*4 + f_][(nh)*2 + g_];                               \
      a_ = mfma_bf16(af[f_][0], BF[g_][0], a_);                                \
      a_ = mfma_bf16(af[f_][1], BF[g_][1], a_);                                \
    }                                                                          \
    __builtin_amdgcn_s_setprio(0);                                             \
  } while (0)

  // Prologue: 7 regions in consume order; A(1,1) is staged in-loop at P1.
  STAGE_A(0, 0); STAGE_B(0, 0); STAGE_B(1, 0); STAGE_A(1, 0);
  STAGE_A(0, 1); STAGE_B(0, 1); STAGE_B(1, 1);
  WAITV(10); BAR(); SCB();

  for (int i = 0; i < 3; ++i) {
    const int o1 = 2 * i + 1, e2 = 2 * i + 2, o3 = 2 * i + 3;
    // P1: reads A0e,B0e ; stage A(1,o) [consumed this iter P7]
    LDA(0, 0); LDB(0, 0, bf0); STAGE_A(1, o1);
    BAR(); MM(0, 0, bf0); WAITV(10); BAR(); SCB();
    // P2: reads B1e ; stage A(0,e+2)
    LDB(0, 1, bf1); STAGE_A(0, e2);
    BAR(); MM(0, 1, bf1); WAITV(10); BAR(); SCB();
    // P3: reads A1e ; stage B(0,e+2)
    LDA(0, 1); STAGE_B(0, e2);
    BAR(); MM(1, 1, bf1); BAR(); SCB();
    // P4: stage B(1,e+2)
    STAGE_B(1, e2);
    BAR(); MM(1, 0, bf0); WAITV(10); BAR(); SCB();
    // P5: reads A0o,B0o ; stage A(1,e+2)
    LDA(1, 0); LDB(1, 0, bf0); STAGE_A(1, e2);
    BAR(); MM(0, 0, bf0); WAITV(10); BAR(); SCB();
    // P6: reads B1o ; stage A(0,o+2)
    LDB(1, 1, bf1); STAGE_A(0, o3);
    BAR(); MM(0, 1, bf1); WAITV(10); BAR(); SCB();
    // P7: reads A1o ; stage B(0,o+2)
    LDA(1, 1); STAGE_B(0, o3);
    BAR(); MM(1, 1, bf1); BAR(); SCB();
    // P8: stage B(1,o+2)
    STAGE_B(1, o3);
    BAR(); MM(1, 0, bf0); WAITV(10); BAR(); SCB();
  }
  // Tail (kt 6,7): only A(1,7) still needs staging (at P1); drain gradually.
  LDA(0, 0); LDB(0, 0, bf0); STAGE_A(1, 7);
  BAR(); MM(0, 0, bf0); WAITV(10); BAR(); SCB();
  LDB(0, 1, bf1);
  BAR(); MM(0, 1, bf1); WAITV(8); BAR(); SCB();
  LDA(0, 1);
  BAR(); MM(1, 1, bf1); BAR(); SCB();
  BAR(); MM(1, 0, bf0); WAITV(4); BAR(); SCB();
  LDA(1, 0); LDB(1, 0, bf0);
  BAR(); MM(0, 0, bf0); WAITV(2); BAR(); SCB();
  LDB(1, 1, bf1);
  BAR(); MM(0, 1, bf1); WAITV(0); BAR(); SCB();
  LDA(1, 1);
  BAR(); MM(1, 1, bf1); BAR(); SCB();
  BAR(); MM(1, 0, bf0);

  // Epilogue
  const int crow = m0 + wm * 64 + q4 * 4;
  const int ccol = n0 + wn * 32 + c16;
  if constexpr (OUT == 0) {
    ushort* C = (ushort*)Cout;
#pragma unroll
    for (int mf = 0; mf < 8; ++mf) {
      const int ro = (mf >> 2) * 128 + (mf & 3) * 16;
#pragma unroll
      for (int r = 0; r < 4; ++r) {
        ushort* cp = C + (size_t)(crow + ro + r) * ldc + ccol;
        cp[0]   = f2bf(acc[mf][0][r]);
        cp[16]  = f2bf(acc[mf][1][r]);
        cp[128] = f2bf(acc[mf][2][r]);
        cp[144] = f2bf(acc[mf][3][r]);
      }
    }
  } else {
    float* C = (float*)Cout;
    const float b0 = bias[ccol], b1 = bias[ccol + 16];
    const float b2 = bias[ccol + 128], b3 = bias[ccol + 144];
#pragma unroll
    for (int mf = 0; mf < 8; ++mf) {
      const int ro = (mf >> 2) * 128 + (mf & 3) * 16;
#pragma unroll
      for (int r = 0; r < 4; ++r) {
        float* cp = C + (size_t)win2orig((uint)(crow + ro + r)) * 512 + ccol;
        cp[0]   = acc[mf][0][r] + b0;
        cp[16]  = acc[mf][1][r] + b1;
        cp[128] = acc[mf][2][r] + b2;
        cp[144] = acc[mf][3][r] + b3;
      }
    }
  }
#undef STAGE_A
#undef STAGE_B
#undef LDA
#undef LDB
#undef MM
}

// per-window attention (window-ordered qkv): one wave per (b, g, head)
__global__ __launch_bounds__(256) void attn_win(const ushort* __restrict__ qkv,
                                                ushort* __restrict__ O) {
  __shared__ __align__(16) ushort p_lds[4][4096];
  __shared__ __align__(16) ushort v_lds[4][4096];
  const int tid = threadIdx.x, lane = tid & 63, w = tid >> 6;
  const int wg = blockIdx.x * 4 + w;
  const int head = wg & 7, g = (wg >> 3) & 63, b = wg >> 9;
  const int c16 = lane & 15, q4 = lane >> 4;
  const size_t wrow = (size_t)b * 3136 + g * 49;  // first token row of window
  const u16x8 Z = {0, 0, 0, 0, 0, 0, 0, 0};

  const int qc = head * 64 + q4 * 8;
  u16x8 qf[2][4], kf[2][4];
#pragma unroll
  for (int i = 0; i < 4; ++i) {
    int s = i * 16 + c16;
    bool val = (s < 49);
    const ushort* p = qkv + (wrow + (val ? s : 0)) * 1536 + qc;
#pragma unroll
    for (int kk = 0; kk < 2; ++kk) {
      qf[kk][i] = val ? *reinterpret_cast<const u16x8*>(p + kk * 32) : Z;
      kf[kk][i] = val ? *reinterpret_cast<const u16x8*>(p + 512 + kk * 32) : Z;
    }
  }

  // stage V^T (XOR-swizzled): lane covers token t = lane
  {
    const ushort* vp = qkv + (wrow + (lane < 49 ? lane : 0)) * 1536 + 1024 + head * 64;
    u16x8 vr[8];
#pragma unroll
    for (int j = 0; j < 8; ++j)
      vr[j] = (lane < 49) ? *reinterpret_cast<const u16x8*>(vp + j * 8) : Z;
#pragma unroll
    for (int d = 0; d < 64; ++d)
      v_lds[w][(d * 64 + lane) ^ ((d & 7) << 3)] = vr[d >> 3][d & 7];
  }

  f32x4 acc[4][4];
#pragma unroll
  for (int m = 0; m < 4; ++m)
#pragma unroll
    for (int n = 0; n < 4; ++n) acc[m][n] = f32x4{0.f, 0.f, 0.f, 0.f};
#pragma unroll
  for (int kk = 0; kk < 2; ++kk)
#pragma unroll
    for (int m = 0; m < 4; ++m)
#pragma unroll
      for (int n = 0; n < 4; ++n)
        acc[m][n] = mfma_bf16(qf[kk][m], kf[kk][n], acc[m][n]);

#pragma unroll
  for (int m = 0; m < 4; ++m)
#pragma unroll
    for (int r = 0; r < 4; ++r) {
      float s0 = acc[m][0][r] * 0.125f;
      float s1 = acc[m][1][r] * 0.125f;
      float s2 = acc[m][2][r] * 0.125f;
      float s3 = (c16 == 0) ? acc[m][3][r] * 0.125f : -1e30f;
      float mx = fmaxf(fmaxf(s0, s1), fmaxf(s2, s3));
#pragma unroll
      for (int off = 1; off < 16; off <<= 1) mx = fmaxf(mx, __shfl_xor(mx, off));
      s0 = __expf(s0 - mx);
      s1 = __expf(s1 - mx);
      s2 = __expf(s2 - mx);
      s3 = (c16 == 0) ? __expf(s3 - mx) : 0.f;
      float sum = s0 + s1 + s2 + s3;
#pragma unroll
      for (int off = 1; off < 16; off <<= 1) sum += __shfl_xor(sum, off);
      float inv = 1.f / sum;
      int row = m * 16 + q4 * 4 + r;
      int rb = row * 64, swz = (row & 7) << 3;
      p_lds[w][(rb + c16) ^ swz]      = f2bf(s0 * inv);
      p_lds[w][(rb + 16 + c16) ^ swz] = f2bf(s1 * inv);
      p_lds[w][(rb + 32 + c16) ^ swz] = f2bf(s2 * inv);
      p_lds[w][(rb + 48 + c16) ^ swz] = f2bf(s3 * inv);
    }
  __syncthreads();

  f32x4 o[4][4];
#pragma unroll
  for (int m = 0; m < 4; ++m)
#pragma unroll
    for (int n = 0; n < 4; ++n) o[m][n] = f32x4{0.f, 0.f, 0.f, 0.f};
#pragma unroll
  for (int kk = 0; kk < 2; ++kk) {
    u16x8 pa[4], vb[4];
#pragma unroll
    for (int m = 0; m < 4; ++m) {
      int row = m * 16 + c16;
      pa[m] = *reinterpret_cast<const u16x8*>(
          &p_lds[w][(row * 64 + kk * 32 + q4 * 8) ^ ((row & 7) << 3)]);
    }
#pragma unroll
    for (int n = 0; n < 4; ++n) {
      int d = n * 16 + c16;
      vb[n] = *reinterpret_cast<const u16x8*>(
          &v_lds[w][(d * 64 + kk * 32 + q4 * 8) ^ ((d & 7) << 3)]);
    }
#pragma unroll
    for (int m = 0; m < 4; ++m)
#pragma unroll
      for (int n = 0; n < 4; ++n) o[m][n] = mfma_bf16(pa[m], vb[n], o[m][n]);
  }

#pragma unroll
  for (int m = 0; m < 4; ++m)
#pragma unroll
    for (int r = 0; r < 4; ++r) {
      int s = m * 16 + q4 * 4 + r;
      if (s < 49) {
        ushort* op = O + (wrow + s) * 512 + head * 64 + c16;
        op[0]  = f2bf(o[m][0][r]);
        op[16] = f2bf(o[m][1][r]);
        op[32] = f2bf(o[m][2][r]);
        op[48] = f2bf(o[m][3][r]);
      }
    }
}

extern "C" void kernel_launch(void* const* d_in, const int* in_sizes, int n_in,
                              void* d_out, int out_size, void* d_ws, size_t ws_size,
                              hipStream_t stream) {
  const float* x      = (const float*)d_in[0];
  const float* w_qkv  = (const float*)d_in[1];
  const float* w_proj = (const float*)d_in[2];
  const float* b_proj = (const float*)d_in[3];
  char* ws = (char*)d_ws;
  ushort* wqkvT  = (ushort*)ws;                       // 1,572,864 B
  ushort* wprojT = (ushort*)(ws + 1572864);           //   524,288 B
  ushort* xb     = (ushort*)(ws + 2097152);           // 102,760,448 B (reused as attn out)
  ushort* qkv    = (ushort*)(ws + 104857600);         // 308,281,344 B
  float* out = (float*)d_out;

  transpose_cvt<<<dim3(48, 16), 256, 0, stream>>>(w_qkv, wqkvT, 512, 1536);
  transpose_cvt<<<dim3(16, 16), 256, 0, stream>>>(w_proj, wprojT, 512, 512);
  cvt_x_win<<<2048, 256, 0, stream>>>(x, xb, 100352 * 512 / 8);
  // GEMM1: 392 mtiles x 6 ntiles = 2352 blocks (294/XCD)
  gemm8p<0><<<2352, 512, 0, stream>>>(xb, wqkvT, (void*)qkv, nullptr, 1536, 6, 294);
  attn_win<<<4096, 256, 0, stream>>>(qkv, xb);
  // GEMM2: 392 x 2 = 784 blocks (98/XCD), rows descattered to original order
  gemm8p<1><<<784, 512, 0, stream>>>(xb, wprojT, (void*)out, b_proj, 512, 2, 98);
}